// Round 2
// baseline (424.650 us; speedup 1.0000x reference)
//
#include <hip/hip_runtime.h>

// out[row][j] = in[row][j] / sum_j(in[row][j]), inv->0 if non-finite.
// One 64-lane wave per 1024-float row: each lane owns 16 floats (4 float4s),
// giving 4 outstanding loads per lane and a barrier-free, LDS-free reduction
// (__shfl_xor butterfly leaves the row total in every lane).
__global__ __launch_bounds__(256) void
normalizer_kernel(const float* __restrict__ in, float* __restrict__ out) {
    const int lane = threadIdx.x & 63;
    const int wave = threadIdx.x >> 6;
    const size_t row = (size_t)blockIdx.x * 4 + wave;

    const float4* __restrict__ rin  = reinterpret_cast<const float4*>(in  + row * 1024);
    float4* __restrict__       rout = reinterpret_cast<float4*>      (out + row * 1024);

    // 4 independent 16B loads per lane, issued back-to-back.
    float4 v0 = rin[lane];
    float4 v1 = rin[lane + 64];
    float4 v2 = rin[lane + 128];
    float4 v3 = rin[lane + 192];

    // 16-value in-register tree sum.
    float s01 = ((v0.x + v0.y) + (v0.z + v0.w)) + ((v1.x + v1.y) + (v1.z + v1.w));
    float s23 = ((v2.x + v2.y) + (v2.z + v2.w)) + ((v3.x + v3.y) + (v3.z + v3.w));
    float s = s01 + s23;

    // 64-lane butterfly: every lane ends with the full row sum.
    #pragma unroll
    for (int off = 32; off > 0; off >>= 1)
        s += __shfl_xor(s, off, 64);

    float inv = 1.0f / s;
    if (!isfinite(inv)) inv = 0.0f;   // remove_nan_inf semantics

    v0.x *= inv; v0.y *= inv; v0.z *= inv; v0.w *= inv;
    v1.x *= inv; v1.y *= inv; v1.z *= inv; v1.w *= inv;
    v2.x *= inv; v2.y *= inv; v2.z *= inv; v2.w *= inv;
    v3.x *= inv; v3.y *= inv; v3.z *= inv; v3.w *= inv;

    rout[lane]       = v0;
    rout[lane + 64]  = v1;
    rout[lane + 128] = v2;
    rout[lane + 192] = v3;
}

extern "C" void kernel_launch(void* const* d_in, const int* in_sizes, int n_in,
                              void* d_out, int out_size, void* d_ws, size_t ws_size,
                              hipStream_t stream) {
    const float* adj = reinterpret_cast<const float*>(d_in[0]);
    float* out = reinterpret_cast<float*>(d_out);
    const int n_rows = in_sizes[0] / 1024;          // 65536
    normalizer_kernel<<<dim3(n_rows / 4), dim3(256), 0, stream>>>(adj, out);
}